// Round 9
// baseline (533.076 us; speedup 1.0000x reference)
//
#include <hip/hip_runtime.h>

#define SN_NA    800
#define SN_F     128
#define SN_G     50
#define SN_MAXP  16384
#define SN_CUT2  25.0f
#define NBLK     256
#define NTHR     256

typedef __attribute__((ext_vector_type(4))) float f32x4;
typedef __attribute__((ext_vector_type(8))) short short8;

// ---- f32 bias offsets (elements, inside wb) ----
#define OB_BF1 0        // [3][128]
#define OB_BF2 384
#define OB_B2  768
#define OB_B3  1152
#define OB_BO1 1536     // [64]
#define OB_WO2 1600     // [64]
#define OB_BO2 1664     // [1]
#define NB_TOT 1665

// ---- bf16 transposed weights (elements, inside wtT): wT[col][k] = W[k][col] ----
#define OT_WF1T 0        // [3][128][64] (k>=50 zero)
#define OT_WF2T 24576    // [3][128][128]
#define OT_W2T  73728    // [3][128][128]
#define OT_W3T  122880   // [3][128][128]
#define OT_WINT 172032   // [3][128][128]
#define OT_WO1T 221184   // [64][128]
#define NT_TOT  229376

// ---- ws layout (bytes) ----
#define MO_PCNT  0
#define MO_BARC  32
#define MO_BARG  36
#define MO_NCLO  64                      // 800*4 -> 3264  (memset 0..3264)
#define MO_NCUP  3264                    // 800*4 -> 6464
#define MO_NBR   6464                    // 800*128*4 -> 416064 (packed p<<10|j)
#define MO_PAIRR 416064                  // 16384*4 -> 481600
#define MO_WB    481600                  // 1665*4 -> 488260
#define MO_WTT   488272                  // 229376*2 -> 947024
#define MO_WPH   947024                  // 3*16384*128*2 -> 13529936
#define MO_X     13529936                // 800*128*4
#define MO_XF    13939536
#define MO_XF2   14349136
#define MO_EPART 14758736                // 256B
#define SN_WSNEED (MO_EPART + 256)

__device__ __forceinline__ float ldr(const void* p, int idx, int bf) {
    if (bf) {
        unsigned int x = ((unsigned int)(((const unsigned short*)p)[idx])) << 16;
        float f; __builtin_memcpy(&f, &x, 4); return f;
    }
    return ((const float*)p)[idx];
}
__device__ __forceinline__ int bfflag(const void* box) {
    float b0 = ((const float*)box)[0];
    return !(b0 > 1e-3f && b0 < 1e3f);
}
__device__ __forceinline__ float bf2f(unsigned short u) {
    unsigned int x = ((unsigned int)u) << 16;
    float f; __builtin_memcpy(&f, &x, 4); return f;
}
__device__ __forceinline__ unsigned short f2bf(float v) {
    unsigned int b; __builtin_memcpy(&b, &v, 4);
    return (unsigned short)((b + 0x7FFFu + ((b >> 16) & 1u)) >> 16);
}
__device__ __forceinline__ float sspf(float v) {
    float sp = fmaxf(v, 0.0f) + log1pf(__expf(-fabsf(v)));
    return sp - 0.69314718055994530942f;
}
// unpack 8 bf16 (uint4) -> 8 f32
__device__ __forceinline__ void u4tof8(uint4 v, float* o) {
    unsigned int w0=v.x, w1=v.y, w2=v.z, w3=v.w;
    unsigned int b;
    b = w0<<16;          __builtin_memcpy(&o[0],&b,4);
    b = w0&0xFFFF0000u;  __builtin_memcpy(&o[1],&b,4);
    b = w1<<16;          __builtin_memcpy(&o[2],&b,4);
    b = w1&0xFFFF0000u;  __builtin_memcpy(&o[3],&b,4);
    b = w2<<16;          __builtin_memcpy(&o[4],&b,4);
    b = w2&0xFFFF0000u;  __builtin_memcpy(&o[5],&b,4);
    b = w3<<16;          __builtin_memcpy(&o[6],&b,4);
    b = w3&0xFFFF0000u;  __builtin_memcpy(&o[7],&b,4);
}

// device-wide sense-reversing barrier (device-scope atomics + fences, G16)
__device__ __forceinline__ void gridbar(int* cnt, int* gen) {
    __syncthreads();
    if (threadIdx.x == 0) {
        __threadfence();
        int g = __hip_atomic_load(gen, __ATOMIC_RELAXED, __HIP_MEMORY_SCOPE_AGENT);
        int a = __hip_atomic_fetch_add(cnt, 1, __ATOMIC_ACQ_REL, __HIP_MEMORY_SCOPE_AGENT);
        if (a == NBLK - 1) {
            __hip_atomic_store(cnt, 0, __ATOMIC_RELAXED, __HIP_MEMORY_SCOPE_AGENT);
            __hip_atomic_store(gen, g + 1, __ATOMIC_RELEASE, __HIP_MEMORY_SCOPE_AGENT);
        } else {
            while (__hip_atomic_load(gen, __ATOMIC_ACQUIRE, __HIP_MEMORY_SCOPE_AGENT) == g)
                __builtin_amdgcn_s_sleep(8);
        }
        __threadfence();
    }
    __syncthreads();
}

__global__ __launch_bounds__(NTHR, 1) void k_mega(
    const void* pos, const void* box, const int* zn, const void* emb,
    const void* wf1, const void* bf1w, const void* wf2, const void* bf2w,
    const void* winm, const void* w2m, const void* b2m,
    const void* w3m, const void* b3m,
    const void* wo1, const void* bo1w, const void* wo2w, const void* bo2w,
    char* ws, void* out)
{
    __shared__ char smraw[22528] __attribute__((aligned(16)));
    // phase-local LDS views
    int*   blj = (int*)smraw;                 // [64]
    float* blr = (float*)(smraw + 256);       // [64]
    int*   bls = (int*)(smraw + 512);         // [2]
    unsigned short (*gls)[72]  = (unsigned short(*)[72])smraw;            // 2304B
    unsigned short (*hls)[136] = (unsigned short(*)[136])(smraw + 2304);  // 4352B
    unsigned int   (*nl)[128]  = (unsigned int(*)[128])smraw;             // 8192B
    unsigned short (*ms)[136]  = (unsigned short(*)[136])(smraw + 8192);
    unsigned short (*ts)[136]  = (unsigned short(*)[136])(smraw + 12544);
    unsigned short (*xs)[136]  = (unsigned short(*)[136])(smraw + 16896);
    float* red = (float*)(smraw + 21248);     // [256]

    int bid = blockIdx.x, tid = threadIdx.x;
    int lane = tid & 63, wave = tid >> 6;
    int rowA = lane & 15, kgrp = lane >> 4;

    int*            pcnt  = (int*)(ws + MO_PCNT);
    int*            barc  = (int*)(ws + MO_BARC);
    int*            barg  = (int*)(ws + MO_BARG);
    int*            nclo  = (int*)(ws + MO_NCLO);
    int*            ncup  = (int*)(ws + MO_NCUP);
    unsigned int*   nbr   = (unsigned int*)(ws + MO_NBR);
    float*          pairr = (float*)(ws + MO_PAIRR);
    float*          wb    = (float*)(ws + MO_WB);
    unsigned short* wtT   = (unsigned short*)(ws + MO_WTT);
    unsigned short* wph   = (unsigned short*)(ws + MO_WPH);
    float*          x     = (float*)(ws + MO_X);
    float*          xfA   = (float*)(ws + MO_XF);
    float*          xfB   = (float*)(ws + MO_XF2);
    float*          epart = (float*)(ws + MO_EPART);

    int bf = bfflag(box);

    // ================= phase 1: setup (0..902) + build (903..1702) =================
    for (int w = bid; w < 1703; w += NBLK) {
        if (w < 7) {                       // biases -> f32
            int t = w*256 + tid;
            if (t < NB_TOT) {
                const int   sz[7] = {384,384,384,384,64,64,1};
                const void* ps[7] = {bf1w,bf2w,b2m,b3m,bo1w,wo2w,bo2w};
                int rem = t, s = 0;
#pragma unroll
                for (int q = 0; q < 7; q++) { if (rem >= sz[q]) { rem -= sz[q]; s = q+1; } else break; }
                wb[t] = ldr(ps[s], rem, bf);
            }
        } else if (w < 903) {              // transposed bf16 weights
            int t = (w-7)*256 + tid;
            float v;
            if (t < OT_WF2T) {
                int lay = t / 8192, rem = t - lay*8192, col = rem >> 6, k = rem & 63;
                v = (k < SN_G) ? ldr(wf1, lay*(SN_G*SN_F) + k*SN_F + col, bf) : 0.0f;
            } else if (t < OT_W2T) {
                int i2 = t - OT_WF2T; int lay = i2 >> 14, rem = i2 & 16383, col = rem >> 7, k = rem & 127;
                v = ldr(wf2, lay*16384 + k*128 + col, bf);
            } else if (t < OT_W3T) {
                int i2 = t - OT_W2T;  int lay = i2 >> 14, rem = i2 & 16383, col = rem >> 7, k = rem & 127;
                v = ldr(w2m, lay*16384 + k*128 + col, bf);
            } else if (t < OT_WINT) {
                int i2 = t - OT_W3T;  int lay = i2 >> 14, rem = i2 & 16383, col = rem >> 7, k = rem & 127;
                v = ldr(w3m, lay*16384 + k*128 + col, bf);
            } else if (t < OT_WO1T) {
                int i2 = t - OT_WINT; int lay = i2 >> 14, rem = i2 & 16383, col = rem >> 7, k = rem & 127;
                v = ldr(winm, lay*16384 + k*128 + col, bf);
            } else {
                int i2 = t - OT_WO1T; int col = i2 >> 7, k = i2 & 127;
                v = ldr(wo1, k*64 + col, bf);
            }
            wtT[t] = f2bf(v);
        } else {                           // build row i
            int i = w - 903;
            __syncthreads();
            if (tid == 0) bls[0] = 0;
            __syncthreads();
            float c00 = ldr(box,0,bf)*10.f, c01 = ldr(box,1,bf)*10.f, c02 = ldr(box,2,bf)*10.f;
            float c10 = ldr(box,3,bf)*10.f, c11 = ldr(box,4,bf)*10.f, c12 = ldr(box,5,bf)*10.f;
            float c20 = ldr(box,6,bf)*10.f, c21 = ldr(box,7,bf)*10.f, c22 = ldr(box,8,bf)*10.f;
            float det = c00*(c11*c22 - c12*c21) - c01*(c10*c22 - c12*c20) + c02*(c10*c21 - c11*c20);
            float id  = 1.0f / det;
            float i00 = (c11*c22 - c12*c21)*id, i01 = (c02*c21 - c01*c22)*id, i02 = (c01*c12 - c02*c11)*id;
            float i10 = (c12*c20 - c10*c22)*id, i11 = (c00*c22 - c02*c20)*id, i12 = (c02*c10 - c00*c12)*id;
            float i20 = (c10*c21 - c11*c20)*id, i21 = (c01*c20 - c00*c21)*id, i22 = (c00*c11 - c01*c10)*id;
            float xi = ldr(pos, i*3+0, bf)*10.f;
            float yi = ldr(pos, i*3+1, bf)*10.f;
            float zi = ldr(pos, i*3+2, bf)*10.f;
            for (int j = i + 1 + tid; j < SN_NA; j += NTHR) {
                float dx = xi - ldr(pos, j*3+0, bf)*10.f;
                float dy = yi - ldr(pos, j*3+1, bf)*10.f;
                float dz = zi - ldr(pos, j*3+2, bf)*10.f;
                float fx = dx*i00 + dy*i10 + dz*i20;
                float fy = dx*i01 + dy*i11 + dz*i21;
                float fz = dx*i02 + dy*i12 + dz*i22;
                fx -= rintf(fx); fy -= rintf(fy); fz -= rintf(fz);
                float ax = fx*c00 + fy*c10 + fz*c20;
                float ay = fx*c01 + fy*c11 + fz*c21;
                float az = fx*c02 + fy*c12 + fz*c22;
                float r2 = ax*ax + ay*ay + az*az;
                if (r2 < SN_CUT2) {
                    int k = atomicAdd(&bls[0], 1);
                    if (k < 64) { blj[k] = j; blr[k] = sqrtf(r2); }
                }
            }
            __syncthreads();
            int cntr = bls[0]; if (cntr > 64) cntr = 64;
            if (tid == 0) bls[1] = atomicAdd(pcnt, cntr);
            __syncthreads();
            int base = bls[1];
            int avail = SN_MAXP - base; if (avail < 0) avail = 0;
            int stored = cntr < avail ? cntr : avail;
            if (tid == 0) ncup[i] = stored;
            if (tid < stored) {
                int p = base + tid, j = blj[tid];
                pairr[p] = blr[tid];
                nbr[i*128 + tid] = ((unsigned int)p << 10) | (unsigned int)j;
                int kj = atomicAdd(&nclo[j], 1);
                if (kj < 64) nbr[j*128 + 64 + kj] = ((unsigned int)p << 10) | (unsigned int)i;
            }
            __syncthreads();
        }
    }
    gridbar(barc, barg);

    // ================= phase 2: init (0..49) + filter tiles =================
    int cnt = __hip_atomic_load(pcnt, __ATOMIC_RELAXED, __HIP_MEMORY_SCOPE_AGENT);
    if (cnt > SN_MAXP) cnt = SN_MAXP;
    int ntile = (cnt + 15) >> 4;
    for (int w = bid; w < 50 + 3*ntile; w += NBLK) {
        __syncthreads();
        if (w < 50) {
            // ---- init: x = emb[zn]; xf0 = x @ Win0 ----
            int a0 = w * 16;
            int a = tid >> 4, f0 = (tid & 15) * 8;
            int atom = a0 + a, z = zn[atom];
            float v[8];
#pragma unroll
            for (int q = 0; q < 8; q++) v[q] = ldr(emb, z*SN_F + f0 + q, bf);
            *(float4*)&x[atom*SN_F + f0]     = make_float4(v[0],v[1],v[2],v[3]);
            *(float4*)&x[atom*SN_F + f0 + 4] = make_float4(v[4],v[5],v[6],v[7]);
#pragma unroll
            for (int q = 0; q < 8; q++) hls[a][f0+q] = f2bf(v[q]);
            __syncthreads();
            int c0 = wave * 32;
            f32x4 acc0 = {0.f,0.f,0.f,0.f}, acc1 = {0.f,0.f,0.f,0.f};
            const unsigned short* wn = wtT + OT_WINT;
#pragma unroll
            for (int ks = 0; ks < 4; ks++) {
                short8 a8 = *(const short8*)&hls[rowA][ks*32 + kgrp*8];
                short8 w0 = *(const short8*)(wn + (c0 + rowA)*128      + ks*32 + kgrp*8);
                short8 w1 = *(const short8*)(wn + (c0 + 16 + rowA)*128 + ks*32 + kgrp*8);
                acc0 = __builtin_amdgcn_mfma_f32_16x16x32_bf16(a8, w0, acc0, 0, 0, 0);
                acc1 = __builtin_amdgcn_mfma_f32_16x16x32_bf16(a8, w1, acc1, 0, 0, 0);
            }
#pragma unroll
            for (int r = 0; r < 4; r++) {
                int row = kgrp*4 + r;
                xfA[(a0 + row)*SN_F + c0 + rowA]      = acc0[r];
                xfA[(a0 + row)*SN_F + c0 + 16 + rowA] = acc1[r];
            }
        } else {
            // ---- filter tile ----
            int f = w - 50;
            int lay = (f >= ntile) + (f >= 2*ntile);
            int t   = f - lay*ntile;
            int p0  = t * 16;
            int c0  = wave * 32;
            {
                const float width = 5.0f/49.0f, gamma = 0.5f/(width*width);
                for (int t2 = tid; t2 < 16*64; t2 += NTHR) {
                    int bb = t2 >> 6, k = t2 & 63;
                    float g = 0.0f;
                    int p = p0 + bb;
                    if (k < SN_G && p < cnt) {
                        float d = pairr[p] - width*(float)k;
                        g = __expf(-gamma*d*d);
                    }
                    gls[bb][k] = f2bf(g);
                }
            }
            __syncthreads();
            f32x4 acc0 = {0.f,0.f,0.f,0.f}, acc1 = {0.f,0.f,0.f,0.f};
            const unsigned short* b1 = wtT + OT_WF1T + lay*8192;
#pragma unroll
            for (int ks = 0; ks < 2; ks++) {
                short8 a8 = *(const short8*)&gls[rowA][ks*32 + kgrp*8];
                short8 w0 = *(const short8*)(b1 + (c0 + rowA)*64      + ks*32 + kgrp*8);
                short8 w1 = *(const short8*)(b1 + (c0 + 16 + rowA)*64 + ks*32 + kgrp*8);
                acc0 = __builtin_amdgcn_mfma_f32_16x16x32_bf16(a8, w0, acc0, 0, 0, 0);
                acc1 = __builtin_amdgcn_mfma_f32_16x16x32_bf16(a8, w1, acc1, 0, 0, 0);
            }
            {
                float b1c0 = wb[OB_BF1 + lay*SN_F + c0 + rowA];
                float b1c1 = wb[OB_BF1 + lay*SN_F + c0 + 16 + rowA];
#pragma unroll
                for (int r = 0; r < 4; r++) {
                    int row = kgrp*4 + r;
                    hls[row][c0 + rowA]      = f2bf(sspf(acc0[r] + b1c0));
                    hls[row][c0 + 16 + rowA] = f2bf(sspf(acc1[r] + b1c1));
                }
            }
            __syncthreads();
            f32x4 d0 = {0.f,0.f,0.f,0.f}, d1 = {0.f,0.f,0.f,0.f};
            const unsigned short* b2w = wtT + OT_WF2T + lay*16384;
#pragma unroll
            for (int ks = 0; ks < 4; ks++) {
                short8 a8 = *(const short8*)&hls[rowA][ks*32 + kgrp*8];
                short8 w0 = *(const short8*)(b2w + (c0 + rowA)*128      + ks*32 + kgrp*8);
                short8 w1 = *(const short8*)(b2w + (c0 + 16 + rowA)*128 + ks*32 + kgrp*8);
                d0 = __builtin_amdgcn_mfma_f32_16x16x32_bf16(a8, w0, d0, 0, 0, 0);
                d1 = __builtin_amdgcn_mfma_f32_16x16x32_bf16(a8, w1, d1, 0, 0, 0);
            }
            {
                unsigned short* wout = wph + lay*(SN_MAXP*SN_F);
                float b2c0 = wb[OB_BF2 + lay*SN_F + c0 + rowA];
                float b2c1 = wb[OB_BF2 + lay*SN_F + c0 + 16 + rowA];
#pragma unroll
                for (int r = 0; r < 4; r++) {
                    int p = p0 + kgrp*4 + r;   // pad rows never referenced by CSR
                    wout[p*SN_F + c0 + rowA]      = f2bf(d0[r] + b2c0);
                    wout[p*SN_F + c0 + 16 + rowA] = f2bf(d1[r] + b2c1);
                }
            }
        }
    }
    gridbar(barc, barg);

    // ================= phases 3-5: layers (50 active blocks) =================
    float* xf_in = xfA;
    float* xf_out = xfB;
    for (int lay = 0; lay < 3; lay++) {
        if (bid < 50) {
            int a0 = bid * 16;
            int a = tid >> 4, sl = tid & 15;
            int atom = a0 + a;
            int up = ncup[atom]; if (up > 64) up = 64;
            int lo = nclo[atom]; if (lo > 64) lo = 64;
            int cn = up + lo;
            for (int k = sl; k < up; k += 16) nl[a][k]      = nbr[atom*128 + k];
            for (int k = sl; k < lo; k += 16) nl[a][up + k] = nbr[atom*128 + 64 + k];
            __syncthreads();

            // gather m = sum_j Wij * xf[j]  (8 features/thread)
            {
                int f0 = sl * 8;
                float acc[8] = {0.f,0.f,0.f,0.f,0.f,0.f,0.f,0.f};
                const unsigned short* wpb = wph + lay*(SN_MAXP*SN_F);
                int k = 0;
                for (; k + 2 <= cn; k += 2) {
                    unsigned int v0 = nl[a][k], v1 = nl[a][k+1];
                    uint4 wv0 = *(const uint4*)(wpb + (v0 >> 10)*SN_F + f0);
                    uint4 wv1 = *(const uint4*)(wpb + (v1 >> 10)*SN_F + f0);
                    const float* x0p = xf_in + (v0 & 1023)*SN_F + f0;
                    const float* x1p = xf_in + (v1 & 1023)*SN_F + f0;
                    float4 xa0 = *(const float4*)x0p, xb0 = *(const float4*)(x0p+4);
                    float4 xa1 = *(const float4*)x1p, xb1 = *(const float4*)(x1p+4);
                    float w0f[8], w1f[8];
                    u4tof8(wv0, w0f); u4tof8(wv1, w1f);
                    acc[0] = fmaf(w0f[0], xa0.x, fmaf(w1f[0], xa1.x, acc[0]));
                    acc[1] = fmaf(w0f[1], xa0.y, fmaf(w1f[1], xa1.y, acc[1]));
                    acc[2] = fmaf(w0f[2], xa0.z, fmaf(w1f[2], xa1.z, acc[2]));
                    acc[3] = fmaf(w0f[3], xa0.w, fmaf(w1f[3], xa1.w, acc[3]));
                    acc[4] = fmaf(w0f[4], xb0.x, fmaf(w1f[4], xb1.x, acc[4]));
                    acc[5] = fmaf(w0f[5], xb0.y, fmaf(w1f[5], xb1.y, acc[5]));
                    acc[6] = fmaf(w0f[6], xb0.z, fmaf(w1f[6], xb1.z, acc[6]));
                    acc[7] = fmaf(w0f[7], xb0.w, fmaf(w1f[7], xb1.w, acc[7]));
                }
                if (k < cn) {
                    unsigned int v0 = nl[a][k];
                    uint4 wv0 = *(const uint4*)(wpb + (v0 >> 10)*SN_F + f0);
                    const float* x0p = xf_in + (v0 & 1023)*SN_F + f0;
                    float4 xa0 = *(const float4*)x0p, xb0 = *(const float4*)(x0p+4);
                    float w0f[8]; u4tof8(wv0, w0f);
                    acc[0] = fmaf(w0f[0], xa0.x, acc[0]);
                    acc[1] = fmaf(w0f[1], xa0.y, acc[1]);
                    acc[2] = fmaf(w0f[2], xa0.z, acc[2]);
                    acc[3] = fmaf(w0f[3], xa0.w, acc[3]);
                    acc[4] = fmaf(w0f[4], xb0.x, acc[4]);
                    acc[5] = fmaf(w0f[5], xb0.y, acc[5]);
                    acc[6] = fmaf(w0f[6], xb0.z, acc[6]);
                    acc[7] = fmaf(w0f[7], xb0.w, acc[7]);
                }
#pragma unroll
                for (int q = 0; q < 8; q++) ms[a][f0+q] = f2bf(acc[q]);
            }
            __syncthreads();

            int c0 = wave * 32;
            // GEMM1: t = ssp(m @ W2 + b2)
            {
                f32x4 A0 = {0.f,0.f,0.f,0.f}, A1 = {0.f,0.f,0.f,0.f};
                const unsigned short* wm = wtT + OT_W2T + lay*16384;
#pragma unroll
                for (int ks = 0; ks < 4; ks++) {
                    short8 a8 = *(const short8*)&ms[rowA][ks*32 + kgrp*8];
                    short8 w0 = *(const short8*)(wm + (c0 + rowA)*128      + ks*32 + kgrp*8);
                    short8 w1 = *(const short8*)(wm + (c0 + 16 + rowA)*128 + ks*32 + kgrp*8);
                    A0 = __builtin_amdgcn_mfma_f32_16x16x32_bf16(a8, w0, A0, 0, 0, 0);
                    A1 = __builtin_amdgcn_mfma_f32_16x16x32_bf16(a8, w1, A1, 0, 0, 0);
                }
                float bc0 = wb[OB_B2 + lay*SN_F + c0 + rowA];
                float bc1 = wb[OB_B2 + lay*SN_F + c0 + 16 + rowA];
#pragma unroll
                for (int r = 0; r < 4; r++) {
                    ts[kgrp*4 + r][c0 + rowA]      = f2bf(sspf(A0[r] + bc0));
                    ts[kgrp*4 + r][c0 + 16 + rowA] = f2bf(sspf(A1[r] + bc1));
                }
            }
            __syncthreads();
            // GEMM2: v = t @ W3 + b3 ; xnew = x + v
            {
                f32x4 A0 = {0.f,0.f,0.f,0.f}, A1 = {0.f,0.f,0.f,0.f};
                const unsigned short* wm = wtT + OT_W3T + lay*16384;
#pragma unroll
                for (int ks = 0; ks < 4; ks++) {
                    short8 a8 = *(const short8*)&ts[rowA][ks*32 + kgrp*8];
                    short8 w0 = *(const short8*)(wm + (c0 + rowA)*128      + ks*32 + kgrp*8);
                    short8 w1 = *(const short8*)(wm + (c0 + 16 + rowA)*128 + ks*32 + kgrp*8);
                    A0 = __builtin_amdgcn_mfma_f32_16x16x32_bf16(a8, w0, A0, 0, 0, 0);
                    A1 = __builtin_amdgcn_mfma_f32_16x16x32_bf16(a8, w1, A1, 0, 0, 0);
                }
                float bc0 = wb[OB_B3 + lay*SN_F + c0 + rowA];
                float bc1 = wb[OB_B3 + lay*SN_F + c0 + 16 + rowA];
#pragma unroll
                for (int r = 0; r < 4; r++) {
                    int row = kgrp*4 + r;
                    float x0o = x[(a0 + row)*SN_F + c0 + rowA];
                    float x1o = x[(a0 + row)*SN_F + c0 + 16 + rowA];
                    float xn0 = x0o + A0[r] + bc0;
                    float xn1 = x1o + A1[r] + bc1;
                    x[(a0 + row)*SN_F + c0 + rowA]      = xn0;
                    x[(a0 + row)*SN_F + c0 + 16 + rowA] = xn1;
                    xs[row][c0 + rowA]      = f2bf(xn0);
                    xs[row][c0 + 16 + rowA] = f2bf(xn1);
                }
            }
            __syncthreads();
            if (lay < 2) {
                // GEMM3: xf_out = xnew @ Win[lay+1]
                f32x4 A0 = {0.f,0.f,0.f,0.f}, A1 = {0.f,0.f,0.f,0.f};
                const unsigned short* wm = wtT + OT_WINT + (lay+1)*16384;
#pragma unroll
                for (int ks = 0; ks < 4; ks++) {
                    short8 a8 = *(const short8*)&xs[rowA][ks*32 + kgrp*8];
                    short8 w0 = *(const short8*)(wm + (c0 + rowA)*128      + ks*32 + kgrp*8);
                    short8 w1 = *(const short8*)(wm + (c0 + 16 + rowA)*128 + ks*32 + kgrp*8);
                    A0 = __builtin_amdgcn_mfma_f32_16x16x32_bf16(a8, w0, A0, 0, 0, 0);
                    A1 = __builtin_amdgcn_mfma_f32_16x16x32_bf16(a8, w1, A1, 0, 0, 0);
                }
#pragma unroll
                for (int r = 0; r < 4; r++) {
                    int row = kgrp*4 + r;
                    xf_out[(a0 + row)*SN_F + c0 + rowA]      = A0[r];
                    xf_out[(a0 + row)*SN_F + c0 + 16 + rowA] = A1[r];
                }
            } else {
                // head fused: e = sum ssp(xnew@Wo1 + bo1) * Wo2 over this tile
                float e = 0.f;
                if (wave < 2) {
                    int c0h = wave * 32;
                    f32x4 H0 = {0.f,0.f,0.f,0.f}, H1 = {0.f,0.f,0.f,0.f};
                    const unsigned short* wm = wtT + OT_WO1T;
#pragma unroll
                    for (int ks = 0; ks < 4; ks++) {
                        short8 a8 = *(const short8*)&xs[rowA][ks*32 + kgrp*8];
                        short8 w0 = *(const short8*)(wm + (c0h + rowA)*128      + ks*32 + kgrp*8);
                        short8 w1 = *(const short8*)(wm + (c0h + 16 + rowA)*128 + ks*32 + kgrp*8);
                        H0 = __builtin_amdgcn_mfma_f32_16x16x32_bf16(a8, w0, H0, 0, 0, 0);
                        H1 = __builtin_amdgcn_mfma_f32_16x16x32_bf16(a8, w1, H1, 0, 0, 0);
                    }
                    float bo0 = wb[OB_BO1 + c0h + rowA],      wo0 = wb[OB_WO2 + c0h + rowA];
                    float bo1c = wb[OB_BO1 + c0h + 16 + rowA], wo1c = wb[OB_WO2 + c0h + 16 + rowA];
#pragma unroll
                    for (int r = 0; r < 4; r++)
                        e += sspf(H0[r] + bo0)*wo0 + sspf(H1[r] + bo1c)*wo1c;
                }
                red[tid] = e;
                __syncthreads();
                for (int wd = 128; wd > 0; wd >>= 1) {
                    if (tid < wd) red[tid] += red[tid + wd];
                    __syncthreads();
                }
                if (tid == 0) epart[bid] = red[0];
            }
        }
        gridbar(barc, barg);
        float* tmp = xf_in; xf_in = xf_out; xf_out = tmp;
    }

    // ================= final reduce (block 0) =================
    if (bid == 0 && tid < 64) {
        float s = (tid < 50) ? epart[tid] : 0.f;
#pragma unroll
        for (int off = 32; off > 0; off >>= 1) s += __shfl_down(s, off, 64);
        if (tid == 0) {
            float v = s + (float)SN_NA * wb[OB_BO2];
            if (bf) ((unsigned short*)out)[0] = f2bf(v);
            else    ((float*)out)[0] = v;
        }
    }
}

__global__ void k_fail(void* out) {
    ((unsigned short*)out)[0] = 0x449A;   // bf16 1234.0 sentinel
}

extern "C" void kernel_launch(void* const* d_in, const int* in_sizes, int n_in,
                              void* d_out, int out_size, void* d_ws, size_t ws_size,
                              hipStream_t stream)
{
    if (ws_size < (size_t)SN_WSNEED) {
        k_fail<<<1, 1, 0, stream>>>(d_out);
        return;
    }
    char* ws = (char*)d_ws;
    // zero pcnt, barrier state, nclo (bytes 0..3264)
    hipMemsetAsync(ws, 0, 3264, stream);
    k_mega<<<NBLK, NTHR, 0, stream>>>(
        d_in[0], d_in[1], (const int*)d_in[2], d_in[3],
        d_in[4], d_in[5], d_in[6], d_in[7],
        d_in[8], d_in[9], d_in[10], d_in[11], d_in[12],
        d_in[13], d_in[14], d_in[15], d_in[16],
        ws, d_out);
}

// Round 10
// 95.789 us; speedup vs baseline: 5.5651x; 5.5651x over previous
//
#include <hip/hip_runtime.h>

#define SN_NA    800
#define SN_F     128
#define SN_G     50
#define SN_MAXP  16384
#define SN_MAXN  128      // row slots: upper [0,64), lower [64,128)
#define SN_CUT2  25.0f

typedef __attribute__((ext_vector_type(4))) float f32x4;
typedef __attribute__((ext_vector_type(8))) short short8;

// ---- f32 bias offsets (elements, inside wb) ----
#define OB_BF1 0        // [3][128]
#define OB_BF2 384
#define OB_B2  768
#define OB_B3  1152
#define OB_BO1 1536     // [64]
#define OB_WO2 1600     // [64]
#define OB_BO2 1664     // [1]
#define NB_TOT 1665

// ---- bf16 transposed weights (elements, inside wtT): wT[col][k] = W[k][col] ----
#define OT_WF1T 0        // [3][128][64] (k>=50 zero)
#define OT_WF2T 24576    // [3][128][128]
#define OT_W2T  73728    // [3][128][128]
#define OT_W3T  122880   // [3][128][128]
#define OT_WINT 172032   // [3][128][128]
#define OT_WO1T 221184   // [64][128]
#define NT_TOT  229376

// ---- ws layout (bytes) ----
#define WO_PCNT  0
#define WO_DONE  32
#define WO_NCLO  64                       // 800*4 -> 3264   (memset 0..3264)
#define WO_NCUP  3264                     // -> 6464
#define WO_NBRP  6464                     // 800*128*4 -> 416064
#define WO_NBRO  416064                   // -> 825664
#define WO_PAIRR 825664                   // 16384*4 -> 891200
#define WO_WB    891200                   // 1665*4 -> 897860
#define WO_WTT   897872                   // 229376*2 -> 1356624
#define WO_WPH   1356624                  // 3*16384*128*2 -> 13939536
#define WO_X     13939536                 // 800*128*4 -> 14349136
#define WO_XF    14349136                 // -> 14758736
#define WO_XF2   14758736                 // -> 15168336
#define WO_EPART 15168336                 // 256B
#define SN_WSNEED (WO_EPART + 256)

__device__ __forceinline__ float ldr(const void* p, int idx, int bf) {
    if (bf) {
        unsigned int x = ((unsigned int)(((const unsigned short*)p)[idx])) << 16;
        float f; __builtin_memcpy(&f, &x, 4); return f;
    }
    return ((const float*)p)[idx];
}
__device__ __forceinline__ int bfflag(const void* box) {
    float b0 = ((const float*)box)[0];    // f32: ~2.3 ; bf16 pair reinterpreted: denormal
    return !(b0 > 1e-3f && b0 < 1e3f);
}
__device__ __forceinline__ float bf2f(unsigned short u) {
    unsigned int x = ((unsigned int)u) << 16;
    float f; __builtin_memcpy(&f, &x, 4); return f;
}
__device__ __forceinline__ unsigned short f2bf(float v) {
    unsigned int b; __builtin_memcpy(&b, &v, 4);
    return (unsigned short)((b + 0x7FFFu + ((b >> 16) & 1u)) >> 16);
}
__device__ __forceinline__ float sspf(float v) {
    float sp = fmaxf(v, 0.0f) + log1pf(__expf(-fabsf(v)));
    return sp - 0.69314718055994530942f;
}

// ---------------- prep: setup (blocks 0..902) + pair/CSR build (903..1702) -----
__global__ void k_prep(const void* pos, const void* box,
                       const void* bf1w, const void* bf2w, const void* b2m, const void* b3m,
                       const void* bo1w, const void* wo2w, const void* bo2w,
                       const void* wf1, const void* wf2, const void* w2m, const void* w3m,
                       const void* winm, const void* wo1,
                       float* wb, unsigned short* wtT,
                       int* pcnt, int* ncup, int* nclo,
                       int* nbrp, int* nbro, float* pairr) {
    __shared__ int   lj[64];
    __shared__ float lr[64];
    __shared__ int   lsh[2];
    int bf = bfflag(box);
    int bid = blockIdx.x, tid = threadIdx.x;

    if (bid < 7) {                      // biases -> f32
        int t = bid * 256 + tid;
        if (t < NB_TOT) {
            const int   sz[7] = {384,384,384,384,64,64,1};
            const void* ps[7] = {bf1w,bf2w,b2m,b3m,bo1w,wo2w,bo2w};
            int rem = t, s = 0;
#pragma unroll
            for (int q = 0; q < 7; q++) { if (rem >= sz[q]) { rem -= sz[q]; s = q+1; } else break; }
            wb[t] = ldr(ps[s], rem, bf);
        }
        return;
    }
    if (bid < 903) {                    // transposed bf16 weights
        int t = (bid - 7) * 256 + tid;
        if (t < NT_TOT) {
            float v;
            if (t < OT_WF2T) {
                int lay = t / 8192, rem = t - lay*8192, col = rem >> 6, k = rem & 63;
                v = (k < SN_G) ? ldr(wf1, lay*(SN_G*SN_F) + k*SN_F + col, bf) : 0.0f;
            } else if (t < OT_W2T) {
                int i2 = t - OT_WF2T; int lay = i2 >> 14, rem = i2 & 16383, col = rem >> 7, k = rem & 127;
                v = ldr(wf2, lay*16384 + k*128 + col, bf);
            } else if (t < OT_W3T) {
                int i2 = t - OT_W2T;  int lay = i2 >> 14, rem = i2 & 16383, col = rem >> 7, k = rem & 127;
                v = ldr(w2m, lay*16384 + k*128 + col, bf);
            } else if (t < OT_WINT) {
                int i2 = t - OT_W3T;  int lay = i2 >> 14, rem = i2 & 16383, col = rem >> 7, k = rem & 127;
                v = ldr(w3m, lay*16384 + k*128 + col, bf);
            } else if (t < OT_WO1T) {
                int i2 = t - OT_WINT; int lay = i2 >> 14, rem = i2 & 16383, col = rem >> 7, k = rem & 127;
                v = ldr(winm, lay*16384 + k*128 + col, bf);
            } else {
                int i2 = t - OT_WO1T; int col = i2 >> 7, k = i2 & 127;
                v = ldr(wo1, k*64 + col, bf);
            }
            wtT[t] = f2bf(v);
        }
        return;
    }

    // ---- build row i (block-aggregated pair reservation) ----
    int i = bid - 903;
    if (tid == 0) lsh[0] = 0;
    float c00 = ldr(box,0,bf)*10.f, c01 = ldr(box,1,bf)*10.f, c02 = ldr(box,2,bf)*10.f;
    float c10 = ldr(box,3,bf)*10.f, c11 = ldr(box,4,bf)*10.f, c12 = ldr(box,5,bf)*10.f;
    float c20 = ldr(box,6,bf)*10.f, c21 = ldr(box,7,bf)*10.f, c22 = ldr(box,8,bf)*10.f;
    float det = c00*(c11*c22 - c12*c21) - c01*(c10*c22 - c12*c20) + c02*(c10*c21 - c11*c20);
    float id  = 1.0f / det;
    float i00 = (c11*c22 - c12*c21)*id, i01 = (c02*c21 - c01*c22)*id, i02 = (c01*c12 - c02*c11)*id;
    float i10 = (c12*c20 - c10*c22)*id, i11 = (c00*c22 - c02*c20)*id, i12 = (c02*c10 - c00*c12)*id;
    float i20 = (c10*c21 - c11*c20)*id, i21 = (c01*c20 - c00*c21)*id, i22 = (c00*c11 - c01*c10)*id;
    float xi = ldr(pos, i*3+0, bf)*10.f;
    float yi = ldr(pos, i*3+1, bf)*10.f;
    float zi = ldr(pos, i*3+2, bf)*10.f;
    __syncthreads();

    for (int j = i + 1 + tid; j < SN_NA; j += 256) {
        float dx = xi - ldr(pos, j*3+0, bf)*10.f;
        float dy = yi - ldr(pos, j*3+1, bf)*10.f;
        float dz = zi - ldr(pos, j*3+2, bf)*10.f;
        float fx = dx*i00 + dy*i10 + dz*i20;
        float fy = dx*i01 + dy*i11 + dz*i21;
        float fz = dx*i02 + dy*i12 + dz*i22;
        fx -= rintf(fx); fy -= rintf(fy); fz -= rintf(fz);
        float ax = fx*c00 + fy*c10 + fz*c20;
        float ay = fx*c01 + fy*c11 + fz*c21;
        float az = fx*c02 + fy*c12 + fz*c22;
        float r2 = ax*ax + ay*ay + az*az;
        if (r2 < SN_CUT2) {
            int k = atomicAdd(&lsh[0], 1);
            if (k < 64) { lj[k] = j; lr[k] = sqrtf(r2); }
        }
    }
    __syncthreads();

    int cnt = lsh[0]; if (cnt > 64) cnt = 64;
    if (tid == 0) lsh[1] = atomicAdd(pcnt, cnt);
    __syncthreads();
    int base = lsh[1];
    int avail = SN_MAXP - base; if (avail < 0) avail = 0;
    int stored = cnt < avail ? cnt : avail;
    if (tid == 0) ncup[i] = stored;

    if (tid < stored) {
        int p = base + tid;
        int j = lj[tid];
        pairr[p] = lr[tid];
        nbrp[i*SN_MAXN + tid] = p;
        nbro[i*SN_MAXN + tid] = j;
        int kj = atomicAdd(&nclo[j], 1);
        if (kj < 64) {
            nbrp[j*SN_MAXN + 64 + kj] = p;
            nbro[j*SN_MAXN + 64 + kj] = i;
        }
    }
}

// ---------------- combined: init (blocks 0..49) + all-layer filter (50..3121) ----
// frags (m89-verified): A row=lane&15,k=(lane>>4)*8+e ; B col=lane&15 ; C col=lane&15,row=(lane>>4)*4+r
__global__ void k_initfilter(const int* zn, const void* emb, const void* box,
                             const float* pairr, const int* pcnt,
                             const float* wb, const unsigned short* wtT,
                             float* x, float* xf, unsigned short* wph) {
    __shared__ unsigned short es[16][136];
    __shared__ unsigned short gls[16][72];
    __shared__ unsigned short hls[16][136];
    int tid  = threadIdx.x;
    int lane = tid & 63;
    int wave = tid >> 6;
    int rowA = lane & 15;
    int kgrp = lane >> 4;

    if (blockIdx.x < 50) {
        // ---- init ----
        int bf = bfflag(box);
        int a0 = blockIdx.x * 16;
        int a = tid >> 4, f0 = (tid & 15) * 8;
        int atom = a0 + a;
        int z = zn[atom];
        float v[8];
#pragma unroll
        for (int q = 0; q < 8; q++) v[q] = ldr(emb, z*SN_F + f0 + q, bf);
        *(float4*)&x[atom*SN_F + f0]     = make_float4(v[0],v[1],v[2],v[3]);
        *(float4*)&x[atom*SN_F + f0 + 4] = make_float4(v[4],v[5],v[6],v[7]);
#pragma unroll
        for (int q = 0; q < 8; q++) es[a][f0+q] = f2bf(v[q]);
        __syncthreads();

        int c0 = wave * 32;
        f32x4 acc0 = {0.f,0.f,0.f,0.f}, acc1 = {0.f,0.f,0.f,0.f};
        const unsigned short* wn = wtT + OT_WINT;   // layer 0
#pragma unroll
        for (int ks = 0; ks < 4; ks++) {
            short8 a8 = *(const short8*)&es[rowA][ks*32 + kgrp*8];
            short8 w0 = *(const short8*)(wn + (c0 + rowA)*128      + ks*32 + kgrp*8);
            short8 w1 = *(const short8*)(wn + (c0 + 16 + rowA)*128 + ks*32 + kgrp*8);
            acc0 = __builtin_amdgcn_mfma_f32_16x16x32_bf16(a8, w0, acc0, 0, 0, 0);
            acc1 = __builtin_amdgcn_mfma_f32_16x16x32_bf16(a8, w1, acc1, 0, 0, 0);
        }
#pragma unroll
        for (int r = 0; r < 4; r++) {
            int row = kgrp*4 + r;
            xf[(a0 + row)*SN_F + c0 + rowA]      = acc0[r];
            xf[(a0 + row)*SN_F + c0 + 16 + rowA] = acc1[r];
        }
        return;
    }

    // ---- filter, all layers ----
    int fb  = blockIdx.x - 50;
    int lay = fb >> 10;
    int p0  = (fb & 1023) * 16;
    int cnt = *pcnt; if (cnt > SN_MAXP) cnt = SN_MAXP;
    if (p0 >= cnt) return;
    int c0 = wave * 32;

    {
        int pr = tid >> 4, k0 = (tid & 15) * 4;
        int p = p0 + pr;
        float r = (p < cnt) ? pairr[p] : -1.0f;
        const float width = 5.0f/49.0f, gamma = 0.5f/(width*width);
        unsigned short gv[4];
#pragma unroll
        for (int q = 0; q < 4; q++) {
            int k = k0 + q;
            float g = 0.f;
            if (k < SN_G && r >= 0.f) { float d = r - width*(float)k; g = __expf(-gamma*d*d); }
            gv[q] = f2bf(g);
        }
        *(unsigned long long*)&gls[pr][k0] = *(unsigned long long*)gv;
    }
    __syncthreads();

    f32x4 acc0 = {0.f,0.f,0.f,0.f}, acc1 = {0.f,0.f,0.f,0.f};
    const unsigned short* b1 = wtT + OT_WF1T + lay*8192;
#pragma unroll
    for (int ks = 0; ks < 2; ks++) {
        short8 a8 = *(const short8*)&gls[rowA][ks*32 + kgrp*8];
        short8 w0 = *(const short8*)(b1 + (c0 + rowA)*64      + ks*32 + kgrp*8);
        short8 w1 = *(const short8*)(b1 + (c0 + 16 + rowA)*64 + ks*32 + kgrp*8);
        acc0 = __builtin_amdgcn_mfma_f32_16x16x32_bf16(a8, w0, acc0, 0, 0, 0);
        acc1 = __builtin_amdgcn_mfma_f32_16x16x32_bf16(a8, w1, acc1, 0, 0, 0);
    }
    {
        float b1c0 = wb[OB_BF1 + lay*SN_F + c0 + rowA];
        float b1c1 = wb[OB_BF1 + lay*SN_F + c0 + 16 + rowA];
#pragma unroll
        for (int r = 0; r < 4; r++) {
            int row = kgrp*4 + r;
            hls[row][c0 + rowA]      = f2bf(sspf(acc0[r] + b1c0));
            hls[row][c0 + 16 + rowA] = f2bf(sspf(acc1[r] + b1c1));
        }
    }
    __syncthreads();

    f32x4 d0 = {0.f,0.f,0.f,0.f}, d1 = {0.f,0.f,0.f,0.f};
    const unsigned short* b2w = wtT + OT_WF2T + lay*16384;
#pragma unroll
    for (int ks = 0; ks < 4; ks++) {
        short8 a8 = *(const short8*)&hls[rowA][ks*32 + kgrp*8];
        short8 w0 = *(const short8*)(b2w + (c0 + rowA)*128      + ks*32 + kgrp*8);
        short8 w1 = *(const short8*)(b2w + (c0 + 16 + rowA)*128 + ks*32 + kgrp*8);
        d0 = __builtin_amdgcn_mfma_f32_16x16x32_bf16(a8, w0, d0, 0, 0, 0);
        d1 = __builtin_amdgcn_mfma_f32_16x16x32_bf16(a8, w1, d1, 0, 0, 0);
    }
    {
        unsigned short* wout = wph + lay*(SN_MAXP*SN_F);
        float b2c0 = wb[OB_BF2 + lay*SN_F + c0 + rowA];
        float b2c1 = wb[OB_BF2 + lay*SN_F + c0 + 16 + rowA];
#pragma unroll
        for (int r = 0; r < 4; r++) {
            int p = p0 + kgrp*4 + r;    // pad rows never referenced by CSR
            wout[p*SN_F + c0 + rowA]      = f2bf(d0[r] + b2c0);
            wout[p*SN_F + c0 + 16 + rowA] = f2bf(d1[r] + b2c1);
        }
    }
}

// ---------------- per-layer: gather + 3 MFMA GEMMs + residual (+ fused head) ----
// 50 blocks x 512 threads (8 waves; wave w owns cols [w*16, w*16+16)).
__global__ void k_layerM(const int* ncup, const int* nclo,
                         const int* nbrp, const int* nbro,
                         const unsigned short* wph, const float* xf_in, float* x,
                         const float* wb, const unsigned short* wtT,
                         int lay, int layNext, float* xf_out,
                         float* epart, int* done, const void* box, void* out) {
    __shared__ int   spA[16][128], sjA[16][128];
    __shared__ unsigned short ms[16][136], ts[16][136], xs[16][136];
    __shared__ float red[512];
    __shared__ int   lastf;
    int tid = threadIdx.x;
    int a0 = blockIdx.x * 16;
    int a = tid >> 5, l32 = tid & 31;
    int atom = a0 + a;
    int up = ncup[atom]; if (up > 64) up = 64;
    int lo = nclo[atom]; if (lo > 64) lo = 64;
    int cn = up + lo;
    for (int k = l32; k < up; k += 32) {
        spA[a][k] = nbrp[atom*SN_MAXN + k];
        sjA[a][k] = nbro[atom*SN_MAXN + k];
    }
    for (int k = l32; k < lo; k += 32) {
        spA[a][up + k] = nbrp[atom*SN_MAXN + 64 + k];
        sjA[a][up + k] = nbro[atom*SN_MAXN + 64 + k];
    }
    __syncthreads();

    // gather m[a][f] = sum_k Wpk[f]*xf[jk][f]
    {
        int f0 = l32 * 4;
        float acc[4] = {0.f,0.f,0.f,0.f};
        const unsigned short* wpb = wph + lay*(SN_MAXP*SN_F);
        int k = 0;
        for (; k + 2 <= cn; k += 2) {
            int p0 = spA[a][k],   j0 = sjA[a][k];
            int p1 = spA[a][k+1], j1 = sjA[a][k+1];
            ushort4 w0 = *(const ushort4*)(wpb + p0*SN_F + f0);
            ushort4 w1 = *(const ushort4*)(wpb + p1*SN_F + f0);
            float4  xa = *(const float4*)(xf_in + j0*SN_F + f0);
            float4  xb = *(const float4*)(xf_in + j1*SN_F + f0);
            acc[0] = fmaf(bf2f(w0.x), xa.x, fmaf(bf2f(w1.x), xb.x, acc[0]));
            acc[1] = fmaf(bf2f(w0.y), xa.y, fmaf(bf2f(w1.y), xb.y, acc[1]));
            acc[2] = fmaf(bf2f(w0.z), xa.z, fmaf(bf2f(w1.z), xb.z, acc[2]));
            acc[3] = fmaf(bf2f(w0.w), xa.w, fmaf(bf2f(w1.w), xb.w, acc[3]));
        }
        if (k < cn) {
            int p0 = spA[a][k], j0 = sjA[a][k];
            ushort4 w0 = *(const ushort4*)(wpb + p0*SN_F + f0);
            float4  xa = *(const float4*)(xf_in + j0*SN_F + f0);
            acc[0] = fmaf(bf2f(w0.x), xa.x, acc[0]);
            acc[1] = fmaf(bf2f(w0.y), xa.y, acc[1]);
            acc[2] = fmaf(bf2f(w0.z), xa.z, acc[2]);
            acc[3] = fmaf(bf2f(w0.w), xa.w, acc[3]);
        }
#pragma unroll
        for (int q = 0; q < 4; q++) ms[a][f0+q] = f2bf(acc[q]);
    }
    __syncthreads();

    int lane = tid & 63;
    int wave = tid >> 6;
    int c0   = wave * 16;
    int rowA = lane & 15;
    int kgrp = lane >> 4;
    int col  = c0 + rowA;

    // GEMM1: t = ssp(m @ W2 + b2)
    {
        f32x4 acc = {0.f,0.f,0.f,0.f};
        const unsigned short* w = wtT + OT_W2T + lay*16384;
#pragma unroll
        for (int ks = 0; ks < 4; ks++) {
            short8 a8 = *(const short8*)&ms[rowA][ks*32 + kgrp*8];
            short8 w8 = *(const short8*)(w + col*128 + ks*32 + kgrp*8);
            acc = __builtin_amdgcn_mfma_f32_16x16x32_bf16(a8, w8, acc, 0, 0, 0);
        }
        float bc = wb[OB_B2 + lay*SN_F + col];
#pragma unroll
        for (int r = 0; r < 4; r++) ts[kgrp*4 + r][col] = f2bf(sspf(acc[r] + bc));
    }
    __syncthreads();

    // GEMM2: v = t @ W3 + b3 ; xnew = x + v
    {
        f32x4 acc = {0.f,0.f,0.f,0.f};
        const unsigned short* w = wtT + OT_W3T + lay*16384;
#pragma unroll
        for (int ks = 0; ks < 4; ks++) {
            short8 a8 = *(const short8*)&ts[rowA][ks*32 + kgrp*8];
            short8 w8 = *(const short8*)(w + col*128 + ks*32 + kgrp*8);
            acc = __builtin_amdgcn_mfma_f32_16x16x32_bf16(a8, w8, acc, 0, 0, 0);
        }
        float bc = wb[OB_B3 + lay*SN_F + col];
#pragma unroll
        for (int r = 0; r < 4; r++) {
            int row = kgrp*4 + r;
            float xnew = x[(a0 + row)*SN_F + col] + acc[r] + bc;
            x[(a0 + row)*SN_F + col] = xnew;
            xs[row][col] = f2bf(xnew);
        }
    }
    __syncthreads();

    if (layNext >= 0) {
        // GEMM3: xf_out = xnew @ Win[layNext]
        f32x4 acc = {0.f,0.f,0.f,0.f};
        const unsigned short* w = wtT + OT_WINT + layNext*16384;
#pragma unroll
        for (int ks = 0; ks < 4; ks++) {
            short8 a8 = *(const short8*)&xs[rowA][ks*32 + kgrp*8];
            short8 w8 = *(const short8*)(w + col*128 + ks*32 + kgrp*8);
            acc = __builtin_amdgcn_mfma_f32_16x16x32_bf16(a8, w8, acc, 0, 0, 0);
        }
#pragma unroll
        for (int r = 0; r < 4; r++)
            xf_out[(a0 + kgrp*4 + r)*SN_F + col] = acc[r];
        return;
    }

    // ---- layer 2: fused head over this block's 16-atom xs tile ----
    float e = 0.f;
    if (wave < 4) {                // head output cols 0..63; wave w -> cols [w*16, w*16+16)
        f32x4 H = {0.f,0.f,0.f,0.f};
        const unsigned short* w = wtT + OT_WO1T;
#pragma unroll
        for (int ks = 0; ks < 4; ks++) {
            short8 a8 = *(const short8*)&xs[rowA][ks*32 + kgrp*8];
            short8 w8 = *(const short8*)(w + col*128 + ks*32 + kgrp*8);
            H = __builtin_amdgcn_mfma_f32_16x16x32_bf16(a8, w8, H, 0, 0, 0);
        }
        float bo = wb[OB_BO1 + col];
        float wo = wb[OB_WO2 + col];
#pragma unroll
        for (int r = 0; r < 4; r++) e += sspf(H[r] + bo) * wo;
    }
    red[tid] = e;
    __syncthreads();
    for (int wd = 256; wd > 0; wd >>= 1) {
        if (tid < wd) red[tid] += red[tid + wd];
        __syncthreads();
    }
    if (tid == 0) {
        epart[blockIdx.x] = red[0];
        __threadfence();                                  // release epart
        int old = atomicAdd(done, 1);                     // device-scope, one-shot
        lastf = (old == 49);
    }
    __syncthreads();
    if (lastf) {
        __threadfence();                                  // acquire others' epart
        if (tid < 64) {
            float s = (tid < 50) ? epart[tid] : 0.f;
#pragma unroll
            for (int off = 32; off > 0; off >>= 1) s += __shfl_down(s, off, 64);
            if (tid == 0) {
                float v = s + (float)SN_NA * wb[OB_BO2];
                if (bfflag(box)) ((unsigned short*)out)[0] = f2bf(v);
                else             ((float*)out)[0] = v;
            }
        }
    }
}

__global__ void k_fail(void* out) {
    ((unsigned short*)out)[0] = 0x449A;   // bf16 1234.0 sentinel
}

extern "C" void kernel_launch(void* const* d_in, const int* in_sizes, int n_in,
                              void* d_out, int out_size, void* d_ws, size_t ws_size,
                              hipStream_t stream)
{
    const void* pos = d_in[0];
    const void* box = d_in[1];
    const int*  zn  = (const int*)d_in[2];
    const void* emb = d_in[3];

    if (ws_size < (size_t)SN_WSNEED) {
        k_fail<<<1, 1, 0, stream>>>(d_out);
        return;
    }

    char* ws = (char*)d_ws;
    int*            pcnt  = (int*)           (ws + WO_PCNT);
    int*            done  = (int*)           (ws + WO_DONE);
    int*            nclo  = (int*)           (ws + WO_NCLO);
    int*            ncup  = (int*)           (ws + WO_NCUP);
    int*            nbrp  = (int*)           (ws + WO_NBRP);
    int*            nbro  = (int*)           (ws + WO_NBRO);
    float*          pairr = (float*)         (ws + WO_PAIRR);
    float*          wb    = (float*)         (ws + WO_WB);
    unsigned short* wtT   = (unsigned short*)(ws + WO_WTT);
    unsigned short* wph   = (unsigned short*)(ws + WO_WPH);
    float*          x     = (float*)         (ws + WO_X);
    float*          xfA   = (float*)         (ws + WO_XF);
    float*          xfB   = (float*)         (ws + WO_XF2);
    float*          epart = (float*)         (ws + WO_EPART);

    // zero pcnt, done, nclo (ws NOT re-poisoned between replays)
    hipMemsetAsync(ws, 0, 3264, stream);

    k_prep<<<1703, 256, 0, stream>>>(pos, box,
        d_in[5], d_in[7], d_in[10], d_in[12], d_in[14], d_in[15], d_in[16],
        d_in[4], d_in[6], d_in[9], d_in[11], d_in[8], d_in[13],
        wb, wtT, pcnt, ncup, nclo, nbrp, nbro, pairr);

    k_initfilter<<<50 + 3*1024, 256, 0, stream>>>(zn, emb, box, pairr, pcnt,
                                                  wb, wtT, x, xfA, wph);

    float* xf_in = xfA;
    float* xf_out = xfB;
    for (int l = 0; l < 3; l++) {
        int layNext = (l < 2) ? (l + 1) : -1;
        k_layerM<<<50, 512, 0, stream>>>(ncup, nclo, nbrp, nbro, wph, xf_in, x,
                                         wb, wtT, l, layNext, xf_out,
                                         epart, done, box, d_out);
        float* t = xf_in; xf_in = xf_out; xf_out = t;
    }
}